// Round 11
// baseline (383.520 us; speedup 1.0000x reference)
//
#include <hip/hip_runtime.h>
#include <hip/hip_fp16.h>

#define D 64
#define NBUK 391      // ceil(100096/256) buckets of 256 nodes (key >> 8)
#define NBIN (2 * NBUK)
#define CHUNK 8192    // edges per block in phase1/phase2 (196 blocks)
#define PBSTRIDE 256  // padded blocks-per-bin stride in transposed per_block

// ---- phase1: per-block coarse histograms, written bin-major (transposed) ----
__global__ __launch_bounds__(256) void phase1_kernel(const int* __restrict__ src,
                                                     const int* __restrict__ dst,
                                                     int* __restrict__ per_block, int E) {
    __shared__ int h[NBIN];
    int tid = (int)threadIdx.x;
    for (int j = tid; j < NBIN; j += 256) h[j] = 0;
    __syncthreads();
    int base = blockIdx.x * CHUNK;
    int cnt = min(CHUNK, E - base);
    for (int k = tid * 4; k < cnt; k += 1024) {
        if (k + 3 < cnt) {
            int4 d4 = *(const int4*)(dst + base + k);
            int4 s4 = *(const int4*)(src + base + k);
            atomicAdd(&h[d4.x >> 8], 1); atomicAdd(&h[d4.y >> 8], 1);
            atomicAdd(&h[d4.z >> 8], 1); atomicAdd(&h[d4.w >> 8], 1);
            atomicAdd(&h[NBUK + (s4.x >> 8)], 1); atomicAdd(&h[NBUK + (s4.y >> 8)], 1);
            atomicAdd(&h[NBUK + (s4.z >> 8)], 1); atomicAdd(&h[NBUK + (s4.w >> 8)], 1);
        } else {
            int kend = (k + 4 < cnt) ? k + 4 : cnt;
            for (int t = k; t < kend; ++t) {
                atomicAdd(&h[dst[base + t] >> 8], 1);
                atomicAdd(&h[NBUK + (src[base + t] >> 8)], 1);
            }
        }
    }
    __syncthreads();
    for (int j = tid; j < NBIN; j += 256) per_block[j * PBSTRIDE + blockIdx.x] = h[j];
}

// ---- scanA (transposed): one wave per bin scans its 196 contiguous counts ----
__global__ __launch_bounds__(256) void scanA_kernel(int* __restrict__ per_block,
                                                    int* __restrict__ total) {
    int wv = (int)threadIdx.x >> 6;
    int lane = (int)threadIdx.x & 63;
    int j = blockIdx.x * 4 + wv;
    if (j >= NBIN) return;
    int* pb = per_block + (size_t)j * PBSTRIDE;
    int4 v = *(const int4*)(pb + lane * 4);   // pad columns are zeroed
    int s1 = v.x + v.y, s2 = s1 + v.z, s3 = s2 + v.w;
    int x = s3;
#pragma unroll
    for (int d = 1; d < 64; d <<= 1) {
        int t = __shfl_up(x, d);
        if (lane >= d) x += t;
    }
    int excl = x - s3;
    int4 r = make_int4(excl, excl + v.x, excl + s1, excl + s2);
    *(int4*)(pb + lane * 4) = r;
    if (lane == 63) total[j] = x;
}

// ---- scanB: exclusive-scan bucket totals for dst and src halves ----
__global__ __launch_bounds__(512) void scanB_kernel(const int* __restrict__ total,
                                                    int* __restrict__ cb_dst,
                                                    int* __restrict__ cb_src) {
    __shared__ int s[512];
    int tid = (int)threadIdx.x;
    for (int half = 0; half < 2; ++half) {
        int v = (tid < NBUK) ? total[half * NBUK + tid] : 0;
        s[tid] = v;
        __syncthreads();
        for (int off = 1; off < 512; off <<= 1) {
            int t = (tid >= off) ? s[tid - off] : 0;
            __syncthreads();
            s[tid] += t;
            __syncthreads();
        }
        int* cb = half ? cb_src : cb_dst;
        if (tid < NBUK) cb[tid] = s[tid] - v;
        if (tid == NBUK - 1) cb[NBUK] = s[tid];
        __syncthreads();
    }
}

// ---- phase2: scatter edges to bucket order via LDS cursors ----
__global__ __launch_bounds__(256) void phase2_kernel(const int* __restrict__ src,
                                                     const int* __restrict__ dst,
                                                     const int* __restrict__ per_block,
                                                     const int* __restrict__ cb_dst,
                                                     const int* __restrict__ cb_src,
                                                     int* __restrict__ pairs,
                                                     unsigned char* __restrict__ skeys, int E) {
    __shared__ int lcur[NBIN];
    int tid = (int)threadIdx.x;
    for (int j = tid; j < NBIN; j += 256)
        lcur[j] = per_block[(size_t)j * PBSTRIDE + blockIdx.x] +
                  (j < NBUK ? cb_dst[j] : cb_src[j - NBUK]);
    __syncthreads();
    int base = blockIdx.x * CHUNK;
    int cnt = min(CHUNK, E - base);
    for (int k = tid * 4; k < cnt; k += 1024) {
        if (k + 3 < cnt) {
            int4 d4 = *(const int4*)(dst + base + k);
            int4 s4 = *(const int4*)(src + base + k);
            int p;
            p = atomicAdd(&lcur[d4.x >> 8], 1); pairs[p] = (s4.x << 8) | (d4.x & 255);
            p = atomicAdd(&lcur[d4.y >> 8], 1); pairs[p] = (s4.y << 8) | (d4.y & 255);
            p = atomicAdd(&lcur[d4.z >> 8], 1); pairs[p] = (s4.z << 8) | (d4.z & 255);
            p = atomicAdd(&lcur[d4.w >> 8], 1); pairs[p] = (s4.w << 8) | (d4.w & 255);
            p = atomicAdd(&lcur[NBUK + (s4.x >> 8)], 1); skeys[p] = (unsigned char)(s4.x & 255);
            p = atomicAdd(&lcur[NBUK + (s4.y >> 8)], 1); skeys[p] = (unsigned char)(s4.y & 255);
            p = atomicAdd(&lcur[NBUK + (s4.z >> 8)], 1); skeys[p] = (unsigned char)(s4.z & 255);
            p = atomicAdd(&lcur[NBUK + (s4.w >> 8)], 1); skeys[p] = (unsigned char)(s4.w & 255);
        } else {
            int kend = (k + 4 < cnt) ? k + 4 : cnt;
            for (int t = k; t < kend; ++t) {
                int dv = dst[base + t], sv = src[base + t];
                int p = atomicAdd(&lcur[dv >> 8], 1);
                pairs[p] = (sv << 8) | (dv & 255);
                p = atomicAdd(&lcur[NBUK + (sv >> 8)], 1);
                skeys[p] = (unsigned char)(sv & 255);
            }
        }
    }
}

// ---- finalize: per bucket, dinv from src-keys; row_ptr + col from dst-pairs;
//      ALSO prescale this bucket's 256 feature rows to fp16 (fused prescale) ----
__global__ __launch_bounds__(256) void finalize_csr_kernel(const int* __restrict__ pairs,
                                                           const unsigned char* __restrict__ skeys,
                                                           const int* __restrict__ cb_dst,
                                                           const int* __restrict__ cb_src,
                                                           const float* __restrict__ feat,
                                                           int* __restrict__ row_ptr,
                                                           int* __restrict__ col,
                                                           float* __restrict__ dinv,
                                                           __half* __restrict__ hs, int N) {
    __shared__ int fine[256];
    __shared__ int lcur[256];
    __shared__ float dsh[256];
    __shared__ int wtot[4], wexcl[4];
    int b = (int)blockIdx.x;
    int tid = (int)threadIdx.x, lane = tid & 63, wv = tid >> 6;
    int g = b * 256 + tid;

    // out-degree -> dinv
    fine[tid] = 0;
    __syncthreads();
    int sb0 = cb_src[b], sb1 = cb_src[b + 1];
    for (int i = sb0 + tid; i < sb1; i += 256) atomicAdd(&fine[skeys[i]], 1);
    __syncthreads();
    float dv_ = 1.0f / fmaxf((float)fine[tid], 1.0f);
    dsh[tid] = dv_;
    if (g < N) dinv[g] = dv_;
    __syncthreads();

    // prescale this bucket's rows: hs[node][:] = half(feat[node][:] * dinv[node])
    {
        int q = tid & 7;                 // 8 threads per row, 8 floats each
        int rbase = tid >> 3;            // 32 rows per pass
        for (int p = 0; p < 8; ++p) {
            int r = p * 32 + rbase;
            int node = b * 256 + r;
            if (node < N) {
                float sc = dsh[r];
                const float4* f = (const float4*)(feat + (size_t)node * D + q * 8);
                float4 v0 = f[0], v1 = f[1];
                __half2 h[4];
                h[0] = __floats2half2_rn(v0.x * sc, v0.y * sc);
                h[1] = __floats2half2_rn(v0.z * sc, v0.w * sc);
                h[2] = __floats2half2_rn(v1.x * sc, v1.y * sc);
                h[3] = __floats2half2_rn(v1.z * sc, v1.w * sc);
                *(float4*)(hs + (size_t)node * D + q * 8) = *(float4*)h;
            }
        }
    }
    __syncthreads();

    // in-degree fine hist
    fine[tid] = 0;
    __syncthreads();
    int cb0 = cb_dst[b], cb1 = cb_dst[b + 1];
    for (int i = cb0 + tid; i < cb1; i += 256) atomicAdd(&fine[pairs[i] & 255], 1);
    __syncthreads();
    int v = fine[tid], x = v;
#pragma unroll
    for (int d = 1; d < 64; d <<= 1) {
        int t = __shfl_up(x, d);
        if (lane >= d) x += t;
    }
    if (lane == 63) wtot[wv] = x;
    __syncthreads();
    if (tid == 0) {
        int a = 0;
#pragma unroll
        for (int k = 0; k < 4; ++k) { wexcl[k] = a; a += wtot[k]; }
    }
    __syncthreads();
    int excl = x - v + wexcl[wv];
    if (g <= N) row_ptr[g] = cb0 + excl;
    lcur[tid] = cb0 + excl;
    __syncthreads();
    for (int i = cb0 + tid; i < cb1; i += 256) {
        int p = pairs[i];
        int pos = atomicAdd(&lcur[p & 255], 1);
        col[pos] = p >> 8;
    }
}

__device__ inline void accum8(float* a, float4 raw) {
    __half2* h = (__half2*)&raw;
#pragma unroll
    for (int k = 0; k < 4; ++k) {
        float2 f = __half22float2(h[k]);
        a[2 * k] += f.x;
        a[2 * k + 1] += f.y;
    }
}

// ---- fused gather(fp16) + GEMM (+ column-sum on final layer) ----
// R10 structure (tile=32 nodes, wave-private LDS rows, no tile barriers,
// grid-stride, dual accumulator) with two changes:
//  * W held as 32 packed __half2 VGPRs -> v_fma_mix GEMM; frees the 64-AGPR
//    block, total regs ~88 -> 5 waves/SIMD occupancy cap (was 4).
//  * launched with FG=ceil(ntiles/3) so every block does <=3 tiles and all
//    blocks are co-resident at the 5-wave cap (no straggler 4th round).
__global__ __launch_bounds__(256) void fused_kernel(const __half* __restrict__ hs_in,
                                                    const int* __restrict__ row_ptr,
                                                    const int* __restrict__ col,
                                                    const float* __restrict__ W,
                                                    const float* __restrict__ bias,
                                                    const float* __restrict__ dinv,
                                                    float* __restrict__ outf,
                                                    __half* __restrict__ outh,
                                                    float* __restrict__ msum,
                                                    int N, int mode) {
    int tid = (int)threadIdx.x;
    int lane = tid & 63;
    int wv = tid >> 6;
    int sg = lane >> 3;       // row-slot 0..7 within wave
    int q = lane & 7;         // 8 lanes per row, 16B (8 halves) each
    int g = wv * 8 + sg;      // LDS row 0..31

    __half2 Wreg[32];         // lane's W column: Wreg[i] = (W[2i][lane], W[2i+1][lane])
#pragma unroll
    for (int k = 0; k < 32; ++k)
        Wreg[k] = __floats2half2_rn(W[(2 * k) * 64 + lane], W[(2 * k + 1) * 64 + lane]);
    float breg = bias[lane];

    __shared__ float aggT[32][68];
    float colacc = 0.0f;

    int ntiles = (N + 31) >> 5;
    for (int tile = blockIdx.x; tile < ntiles; tile += gridDim.x) {
        int node_g = tile * 32 + g;
        float a[8];
#pragma unroll
        for (int k = 0; k < 8; ++k) a[k] = 0.0f;
        if (node_g < N) {
            int beg = row_ptr[node_g], end = row_ptr[node_g + 1];
            int j = beg;
            for (; j + 3 < end; j += 4) {
                int s0 = col[j], s1 = col[j + 1], s2 = col[j + 2], s3 = col[j + 3];
                float4 r0 = *(const float4*)(hs_in + (size_t)s0 * D + q * 8);
                float4 r1 = *(const float4*)(hs_in + (size_t)s1 * D + q * 8);
                float4 r2 = *(const float4*)(hs_in + (size_t)s2 * D + q * 8);
                float4 r3 = *(const float4*)(hs_in + (size_t)s3 * D + q * 8);
                accum8(a, r0); accum8(a, r1); accum8(a, r2); accum8(a, r3);
            }
            for (; j < end; ++j) {
                int s0 = col[j];
                float4 r0 = *(const float4*)(hs_in + (size_t)s0 * D + q * 8);
                accum8(a, r0);
            }
        }
        *(float4*)(&aggT[g][q * 8]) = make_float4(a[0], a[1], a[2], a[3]);
        *(float4*)(&aggT[g][q * 8 + 4]) = make_float4(a[4], a[5], a[6], a[7]);

#pragma unroll
        for (int rr = 0; rr < 8; ++rr) {
            int r = wv * 8 + rr;
            int node = tile * 32 + r;
            if (node < N) {
                float acc0 = breg, acc1 = 0.0f;
                const float4* Ar = (const float4*)(&aggT[r][0]);
#pragma unroll
                for (int k4 = 0; k4 < 16; k4 += 2) {
                    float4 av0 = Ar[k4];       // broadcast ds_read_b128, same-wave data
                    float4 av1 = Ar[k4 + 1];
                    __half2 w01 = Wreg[k4 * 2];
                    __half2 w23 = Wreg[k4 * 2 + 1];
                    __half2 w45 = Wreg[k4 * 2 + 2];
                    __half2 w67 = Wreg[k4 * 2 + 3];
                    acc0 = fmaf(av0.x, __low2float(w01), acc0);    // v_fma_mix
                    acc0 = fmaf(av0.y, __high2float(w01), acc0);
                    acc0 = fmaf(av0.z, __low2float(w23), acc0);
                    acc0 = fmaf(av0.w, __high2float(w23), acc0);
                    acc1 = fmaf(av1.x, __low2float(w45), acc1);
                    acc1 = fmaf(av1.y, __high2float(w45), acc1);
                    acc1 = fmaf(av1.z, __low2float(w67), acc1);
                    acc1 = fmaf(av1.w, __high2float(w67), acc1);
                }
                float acc = acc0 + acc1;
                if (mode == 0) {
                    acc = fmaxf(acc, 0.0f) * dinv[node];
                    outh[(size_t)node * D + lane] = __float2half(acc);
                } else {
                    colacc += acc;
                    outf[(size_t)node * D + lane] = acc;
                }
            }
        }
    }

    if (mode == 1) {
        __shared__ float red[256];
        red[tid] = colacc;
        __syncthreads();
        if (wv == 0) {
            float s = red[lane] + red[64 + lane] + red[128 + lane] + red[192 + lane];
            atomicAdd(&msum[lane], s);
        }
    }
}

__global__ void finalize_kernel(const float* __restrict__ msum, float* __restrict__ outMean,
                                float invN) {
    outMean[threadIdx.x] = msum[threadIdx.x] * invN;
}

extern "C" void kernel_launch(void* const* d_in, const int* in_sizes, int n_in,
                              void* d_out, int out_size, void* d_ws, size_t ws_size,
                              hipStream_t stream) {
    const float* feat = (const float*)d_in[0];
    const int* src = (const int*)d_in[1];
    const int* dst = (const int*)d_in[2];
    const float* W0 = (const float*)d_in[3];
    const float* b0 = (const float*)d_in[4];
    const float* W1 = (const float*)d_in[5];
    const float* b1 = (const float*)d_in[6];
    const float* W2 = (const float*)d_in[7];
    const float* b2 = (const float*)d_in[8];

    const int N = in_sizes[0] / D;  // 100000
    const int E = in_sizes[1];      // 1600000
    float* out = (float*)d_out;     // [N*D + D] floats

    const int NBLK = (E + CHUNK - 1) / CHUNK;  // 196 <= PBSTRIDE

    // workspace layout (int units), 16B-aligned offsets; NA = padded N+1
    int* wsi = (int*)d_ws;
    const size_t NA = 100352;
    int*   row_ptr  = wsi;                       // NA
    float* dinv     = (float*)(wsi + NA);        // NA
    float* msum     = (float*)(wsi + 2 * NA);    // 64 (pad 256)
    int*   total    = wsi + 2 * NA + 256;        // 782 (pad 1024)
    int*   cb_dst   = wsi + 2 * NA + 1280;       // 392 (pad 512)
    int*   cb_src   = wsi + 2 * NA + 1792;       // 392 (pad 512)
    int*   per_blk  = wsi + 2 * NA + 2304;       // NBIN*PBSTRIDE = 200192 (pad 200704)
    int*   pairs    = wsi + 2 * NA + 203008;     // E
    unsigned char* skeys = (unsigned char*)(pairs + (size_t)E);  // E bytes (pad -> 400000 ints)
    int*   col      = pairs + (size_t)E + 400000;                // E
    __half* hsA     = (__half*)(col + (size_t)E);                // N*D halves
    __half* hsB     = hsA + (size_t)N * D;                       // N*D halves

    hipMemsetAsync(msum, 0, sizeof(float) * D, stream);
    hipMemsetAsync(per_blk, 0, sizeof(int) * (size_t)NBIN * PBSTRIDE, stream);

    phase1_kernel<<<NBLK, 256, 0, stream>>>(src, dst, per_blk, E);
    scanA_kernel<<<(NBIN + 3) / 4, 256, 0, stream>>>(per_blk, total);
    scanB_kernel<<<1, 512, 0, stream>>>(total, cb_dst, cb_src);
    phase2_kernel<<<NBLK, 256, 0, stream>>>(src, dst, per_blk, cb_dst, cb_src, pairs, skeys, E);
    finalize_csr_kernel<<<NBUK, 256, 0, stream>>>(pairs, skeys, cb_dst, cb_src, feat,
                                                  row_ptr, col, dinv, hsA, N);

    const int ntiles = (N + 31) / 32;          // 3125
    const int FG = (ntiles + 2) / 3;           // 1042: <=3 tiles/block, all co-resident @5 waves/SIMD
    fused_kernel<<<FG, 256, 0, stream>>>(hsA, row_ptr, col, W0, b0, dinv, nullptr, hsB, msum, N, 0);
    fused_kernel<<<FG, 256, 0, stream>>>(hsB, row_ptr, col, W1, b1, dinv, nullptr, hsA, msum, N, 0);
    fused_kernel<<<FG, 256, 0, stream>>>(hsA, row_ptr, col, W2, b2, dinv, out, nullptr, msum, N, 1);

    finalize_kernel<<<1, 64, 0, stream>>>(msum, out + (size_t)N * D, 1.0f / (float)N);
}

// Round 12
// 324.444 us; speedup vs baseline: 1.1821x; 1.1821x over previous
//
#include <hip/hip_runtime.h>
#include <hip/hip_fp16.h>

#define D 64
#define NBUK 391      // ceil(100096/256) buckets of 256 nodes (key >> 8)
#define NBIN (2 * NBUK)
#define CHUNK 8192    // edges per block in phase1/phase2 (196 blocks)
#define PBSTRIDE 256  // padded blocks-per-bin stride in transposed per_block

// ---- phase1: per-block coarse histograms, written bin-major (transposed) ----
__global__ __launch_bounds__(256) void phase1_kernel(const int* __restrict__ src,
                                                     const int* __restrict__ dst,
                                                     int* __restrict__ per_block, int E) {
    __shared__ int h[NBIN];
    int tid = (int)threadIdx.x;
    for (int j = tid; j < NBIN; j += 256) h[j] = 0;
    __syncthreads();
    int base = blockIdx.x * CHUNK;
    int cnt = min(CHUNK, E - base);
    for (int k = tid * 4; k < cnt; k += 1024) {
        if (k + 3 < cnt) {
            int4 d4 = *(const int4*)(dst + base + k);
            int4 s4 = *(const int4*)(src + base + k);
            atomicAdd(&h[d4.x >> 8], 1); atomicAdd(&h[d4.y >> 8], 1);
            atomicAdd(&h[d4.z >> 8], 1); atomicAdd(&h[d4.w >> 8], 1);
            atomicAdd(&h[NBUK + (s4.x >> 8)], 1); atomicAdd(&h[NBUK + (s4.y >> 8)], 1);
            atomicAdd(&h[NBUK + (s4.z >> 8)], 1); atomicAdd(&h[NBUK + (s4.w >> 8)], 1);
        } else {
            int kend = (k + 4 < cnt) ? k + 4 : cnt;
            for (int t = k; t < kend; ++t) {
                atomicAdd(&h[dst[base + t] >> 8], 1);
                atomicAdd(&h[NBUK + (src[base + t] >> 8)], 1);
            }
        }
    }
    __syncthreads();
    for (int j = tid; j < NBIN; j += 256) per_block[j * PBSTRIDE + blockIdx.x] = h[j];
}

// ---- scanA (transposed): one wave per bin scans its 196 contiguous counts ----
__global__ __launch_bounds__(256) void scanA_kernel(int* __restrict__ per_block,
                                                    int* __restrict__ total) {
    int wv = (int)threadIdx.x >> 6;
    int lane = (int)threadIdx.x & 63;
    int j = blockIdx.x * 4 + wv;
    if (j >= NBIN) return;
    int* pb = per_block + (size_t)j * PBSTRIDE;
    int4 v = *(const int4*)(pb + lane * 4);   // pad columns are zeroed
    int s1 = v.x + v.y, s2 = s1 + v.z, s3 = s2 + v.w;
    int x = s3;
#pragma unroll
    for (int d = 1; d < 64; d <<= 1) {
        int t = __shfl_up(x, d);
        if (lane >= d) x += t;
    }
    int excl = x - s3;
    int4 r = make_int4(excl, excl + v.x, excl + s1, excl + s2);
    *(int4*)(pb + lane * 4) = r;
    if (lane == 63) total[j] = x;
}

// ---- scanB: exclusive-scan bucket totals for dst and src halves; zero msum ----
__global__ __launch_bounds__(512) void scanB_kernel(const int* __restrict__ total,
                                                    int* __restrict__ cb_dst,
                                                    int* __restrict__ cb_src,
                                                    float* __restrict__ msum) {
    __shared__ int s[512];
    int tid = (int)threadIdx.x;
    if (tid < D) msum[tid] = 0.0f;   // runs long before fused mode-1 atomics
    for (int half = 0; half < 2; ++half) {
        int v = (tid < NBUK) ? total[half * NBUK + tid] : 0;
        s[tid] = v;
        __syncthreads();
        for (int off = 1; off < 512; off <<= 1) {
            int t = (tid >= off) ? s[tid - off] : 0;
            __syncthreads();
            s[tid] += t;
            __syncthreads();
        }
        int* cb = half ? cb_src : cb_dst;
        if (tid < NBUK) cb[tid] = s[tid] - v;
        if (tid == NBUK - 1) cb[NBUK] = s[tid];
        __syncthreads();
    }
}

// ---- phase2: scatter edges to bucket order via LDS cursors ----
__global__ __launch_bounds__(256) void phase2_kernel(const int* __restrict__ src,
                                                     const int* __restrict__ dst,
                                                     const int* __restrict__ per_block,
                                                     const int* __restrict__ cb_dst,
                                                     const int* __restrict__ cb_src,
                                                     int* __restrict__ pairs,
                                                     unsigned char* __restrict__ skeys, int E) {
    __shared__ int lcur[NBIN];
    int tid = (int)threadIdx.x;
    for (int j = tid; j < NBIN; j += 256)
        lcur[j] = per_block[(size_t)j * PBSTRIDE + blockIdx.x] +
                  (j < NBUK ? cb_dst[j] : cb_src[j - NBUK]);
    __syncthreads();
    int base = blockIdx.x * CHUNK;
    int cnt = min(CHUNK, E - base);
    for (int k = tid * 4; k < cnt; k += 1024) {
        if (k + 3 < cnt) {
            int4 d4 = *(const int4*)(dst + base + k);
            int4 s4 = *(const int4*)(src + base + k);
            int p;
            p = atomicAdd(&lcur[d4.x >> 8], 1); pairs[p] = (s4.x << 8) | (d4.x & 255);
            p = atomicAdd(&lcur[d4.y >> 8], 1); pairs[p] = (s4.y << 8) | (d4.y & 255);
            p = atomicAdd(&lcur[d4.z >> 8], 1); pairs[p] = (s4.z << 8) | (d4.z & 255);
            p = atomicAdd(&lcur[d4.w >> 8], 1); pairs[p] = (s4.w << 8) | (d4.w & 255);
            p = atomicAdd(&lcur[NBUK + (s4.x >> 8)], 1); skeys[p] = (unsigned char)(s4.x & 255);
            p = atomicAdd(&lcur[NBUK + (s4.y >> 8)], 1); skeys[p] = (unsigned char)(s4.y & 255);
            p = atomicAdd(&lcur[NBUK + (s4.z >> 8)], 1); skeys[p] = (unsigned char)(s4.z & 255);
            p = atomicAdd(&lcur[NBUK + (s4.w >> 8)], 1); skeys[p] = (unsigned char)(s4.w & 255);
        } else {
            int kend = (k + 4 < cnt) ? k + 4 : cnt;
            for (int t = k; t < kend; ++t) {
                int dv = dst[base + t], sv = src[base + t];
                int p = atomicAdd(&lcur[dv >> 8], 1);
                pairs[p] = (sv << 8) | (dv & 255);
                p = atomicAdd(&lcur[NBUK + (sv >> 8)], 1);
                skeys[p] = (unsigned char)(sv & 255);
            }
        }
    }
}

// ---- finalize: per bucket, dinv from src-keys; row_ptr + col from dst-pairs;
//      ALSO prescale this bucket's 256 feature rows to fp16 (fused prescale) ----
__global__ __launch_bounds__(256) void finalize_csr_kernel(const int* __restrict__ pairs,
                                                           const unsigned char* __restrict__ skeys,
                                                           const int* __restrict__ cb_dst,
                                                           const int* __restrict__ cb_src,
                                                           const float* __restrict__ feat,
                                                           int* __restrict__ row_ptr,
                                                           int* __restrict__ col,
                                                           float* __restrict__ dinv,
                                                           __half* __restrict__ hs, int N) {
    __shared__ int fine[256];
    __shared__ int lcur[256];
    __shared__ float dsh[256];
    __shared__ int wtot[4], wexcl[4];
    int b = (int)blockIdx.x;
    int tid = (int)threadIdx.x, lane = tid & 63, wv = tid >> 6;
    int g = b * 256 + tid;

    // out-degree -> dinv
    fine[tid] = 0;
    __syncthreads();
    int sb0 = cb_src[b], sb1 = cb_src[b + 1];
    for (int i = sb0 + tid; i < sb1; i += 256) atomicAdd(&fine[skeys[i]], 1);
    __syncthreads();
    float dv_ = 1.0f / fmaxf((float)fine[tid], 1.0f);
    dsh[tid] = dv_;
    if (g < N) dinv[g] = dv_;
    __syncthreads();

    // prescale this bucket's rows: hs[node][:] = half(feat[node][:] * dinv[node])
    {
        int q = tid & 7;                 // 8 threads per row, 8 floats each
        int rbase = tid >> 3;            // 32 rows per pass
        for (int p = 0; p < 8; ++p) {
            int r = p * 32 + rbase;
            int node = b * 256 + r;
            if (node < N) {
                float sc = dsh[r];
                const float4* f = (const float4*)(feat + (size_t)node * D + q * 8);
                float4 v0 = f[0], v1 = f[1];
                __half2 h[4];
                h[0] = __floats2half2_rn(v0.x * sc, v0.y * sc);
                h[1] = __floats2half2_rn(v0.z * sc, v0.w * sc);
                h[2] = __floats2half2_rn(v1.x * sc, v1.y * sc);
                h[3] = __floats2half2_rn(v1.z * sc, v1.w * sc);
                *(float4*)(hs + (size_t)node * D + q * 8) = *(float4*)h;
            }
        }
    }
    __syncthreads();

    // in-degree fine hist
    fine[tid] = 0;
    __syncthreads();
    int cb0 = cb_dst[b], cb1 = cb_dst[b + 1];
    for (int i = cb0 + tid; i < cb1; i += 256) atomicAdd(&fine[pairs[i] & 255], 1);
    __syncthreads();
    int v = fine[tid], x = v;
#pragma unroll
    for (int d = 1; d < 64; d <<= 1) {
        int t = __shfl_up(x, d);
        if (lane >= d) x += t;
    }
    if (lane == 63) wtot[wv] = x;
    __syncthreads();
    if (tid == 0) {
        int a = 0;
#pragma unroll
        for (int k = 0; k < 4; ++k) { wexcl[k] = a; a += wtot[k]; }
    }
    __syncthreads();
    int excl = x - v + wexcl[wv];
    if (g <= N) row_ptr[g] = cb0 + excl;
    lcur[tid] = cb0 + excl;
    __syncthreads();
    for (int i = cb0 + tid; i < cb1; i += 256) {
        int p = pairs[i];
        int pos = atomicAdd(&lcur[p & 255], 1);
        col[pos] = p >> 8;
    }
}

__device__ inline void accum8(float* a, float4 raw) {
    __half2* h = (__half2*)&raw;
#pragma unroll
    for (int k = 0; k < 4; ++k) {
        float2 f = __half22float2(h[k]);
        a[2 * k] += f.x;
        a[2 * k + 1] += f.y;
    }
}

// ---- fused gather(fp16) + GEMM (+ column-sum on final layer) ----
// R10-exact proven config: tile=32 nodes, wave wv owns LDS rows 8wv..8wv+7
// (8 lanes x 16B = one fp16 row), no barriers in tile loop, 4-deep gather
// unroll, fp32 Wreg[64] (lives in AGPRs via unified file), dual accumulator.
// HARD RULE (R6/R8/R11 post-mortems): grid must be <= resident capacity.
// At 128 regs/thread -> 4 waves/SIMD -> exactly 1024 co-resident blocks;
// FG > 1024 creates a serial tail round (+19us measured at FG=1042).
__global__ __launch_bounds__(256) void fused_kernel(const __half* __restrict__ hs_in,
                                                    const int* __restrict__ row_ptr,
                                                    const int* __restrict__ col,
                                                    const float* __restrict__ W,
                                                    const float* __restrict__ bias,
                                                    const float* __restrict__ dinv,
                                                    float* __restrict__ outf,
                                                    __half* __restrict__ outh,
                                                    float* __restrict__ msum,
                                                    int N, int mode) {
    int tid = (int)threadIdx.x;
    int lane = tid & 63;
    int wv = tid >> 6;
    int sg = lane >> 3;       // row-slot 0..7 within wave
    int q = lane & 7;         // 8 lanes per row, 16B (8 halves) each
    int g = wv * 8 + sg;      // LDS row 0..31

    float Wreg[64];
#pragma unroll
    for (int k = 0; k < 64; ++k) Wreg[k] = W[k * 64 + lane];
    float breg = bias[lane];

    __shared__ float aggT[32][68];
    float colacc = 0.0f;

    int ntiles = (N + 31) >> 5;
    for (int tile = blockIdx.x; tile < ntiles; tile += gridDim.x) {
        int node_g = tile * 32 + g;
        float a[8];
#pragma unroll
        for (int k = 0; k < 8; ++k) a[k] = 0.0f;
        if (node_g < N) {
            int beg = row_ptr[node_g], end = row_ptr[node_g + 1];
            int j = beg;
            for (; j + 3 < end; j += 4) {
                int s0 = col[j], s1 = col[j + 1], s2 = col[j + 2], s3 = col[j + 3];
                float4 r0 = *(const float4*)(hs_in + (size_t)s0 * D + q * 8);
                float4 r1 = *(const float4*)(hs_in + (size_t)s1 * D + q * 8);
                float4 r2 = *(const float4*)(hs_in + (size_t)s2 * D + q * 8);
                float4 r3 = *(const float4*)(hs_in + (size_t)s3 * D + q * 8);
                accum8(a, r0); accum8(a, r1); accum8(a, r2); accum8(a, r3);
            }
            for (; j < end; ++j) {
                int s0 = col[j];
                float4 r0 = *(const float4*)(hs_in + (size_t)s0 * D + q * 8);
                accum8(a, r0);
            }
        }
        *(float4*)(&aggT[g][q * 8]) = make_float4(a[0], a[1], a[2], a[3]);
        *(float4*)(&aggT[g][q * 8 + 4]) = make_float4(a[4], a[5], a[6], a[7]);

#pragma unroll
        for (int rr = 0; rr < 8; ++rr) {
            int r = wv * 8 + rr;
            int node = tile * 32 + r;
            if (node < N) {
                float acc0 = breg, acc1 = 0.0f;
                const float4* Ar = (const float4*)(&aggT[r][0]);
#pragma unroll
                for (int k4 = 0; k4 < 16; k4 += 2) {
                    float4 av0 = Ar[k4];       // broadcast ds_read_b128, same-wave data
                    float4 av1 = Ar[k4 + 1];
                    acc0 = fmaf(av0.x, Wreg[k4 * 4 + 0], acc0);
                    acc0 = fmaf(av0.y, Wreg[k4 * 4 + 1], acc0);
                    acc0 = fmaf(av0.z, Wreg[k4 * 4 + 2], acc0);
                    acc0 = fmaf(av0.w, Wreg[k4 * 4 + 3], acc0);
                    acc1 = fmaf(av1.x, Wreg[k4 * 4 + 4], acc1);
                    acc1 = fmaf(av1.y, Wreg[k4 * 4 + 5], acc1);
                    acc1 = fmaf(av1.z, Wreg[k4 * 4 + 6], acc1);
                    acc1 = fmaf(av1.w, Wreg[k4 * 4 + 7], acc1);
                }
                float acc = acc0 + acc1;
                if (mode == 0) {
                    acc = fmaxf(acc, 0.0f) * dinv[node];
                    outh[(size_t)node * D + lane] = __float2half(acc);
                } else {
                    colacc += acc;
                    outf[(size_t)node * D + lane] = acc;
                }
            }
        }
    }

    if (mode == 1) {
        __shared__ float red[256];
        red[tid] = colacc;
        __syncthreads();
        if (wv == 0) {
            float s = red[lane] + red[64 + lane] + red[128 + lane] + red[192 + lane];
            atomicAdd(&msum[lane], s);
        }
    }
}

__global__ void finalize_kernel(const float* __restrict__ msum, float* __restrict__ outMean,
                                float invN) {
    outMean[threadIdx.x] = msum[threadIdx.x] * invN;
}

extern "C" void kernel_launch(void* const* d_in, const int* in_sizes, int n_in,
                              void* d_out, int out_size, void* d_ws, size_t ws_size,
                              hipStream_t stream) {
    const float* feat = (const float*)d_in[0];
    const int* src = (const int*)d_in[1];
    const int* dst = (const int*)d_in[2];
    const float* W0 = (const float*)d_in[3];
    const float* b0 = (const float*)d_in[4];
    const float* W1 = (const float*)d_in[5];
    const float* b1 = (const float*)d_in[6];
    const float* W2 = (const float*)d_in[7];
    const float* b2 = (const float*)d_in[8];

    const int N = in_sizes[0] / D;  // 100000
    const int E = in_sizes[1];      // 1600000
    float* out = (float*)d_out;     // [N*D + D] floats

    const int NBLK = (E + CHUNK - 1) / CHUNK;  // 196 <= PBSTRIDE

    // workspace layout (int units), 16B-aligned offsets; NA = padded N+1
    int* wsi = (int*)d_ws;
    const size_t NA = 100352;
    int*   row_ptr  = wsi;                       // NA
    float* dinv     = (float*)(wsi + NA);        // NA
    float* msum     = (float*)(wsi + 2 * NA);    // 64 (pad 256)
    int*   total    = wsi + 2 * NA + 256;        // 782 (pad 1024)
    int*   cb_dst   = wsi + 2 * NA + 1280;       // 392 (pad 512)
    int*   cb_src   = wsi + 2 * NA + 1792;       // 392 (pad 512)
    int*   per_blk  = wsi + 2 * NA + 2304;       // NBIN*PBSTRIDE = 200192 (pad 200704)
    int*   pairs    = wsi + 2 * NA + 203008;     // E
    unsigned char* skeys = (unsigned char*)(pairs + (size_t)E);  // E bytes (pad -> 400000 ints)
    int*   col      = pairs + (size_t)E + 400000;                // E
    __half* hsA     = (__half*)(col + (size_t)E);                // N*D halves
    __half* hsB     = hsA + (size_t)N * D;                       // N*D halves

    hipMemsetAsync(per_blk, 0, sizeof(int) * (size_t)NBIN * PBSTRIDE, stream);

    phase1_kernel<<<NBLK, 256, 0, stream>>>(src, dst, per_blk, E);
    scanA_kernel<<<(NBIN + 3) / 4, 256, 0, stream>>>(per_blk, total);
    scanB_kernel<<<1, 512, 0, stream>>>(total, cb_dst, cb_src, msum);
    phase2_kernel<<<NBLK, 256, 0, stream>>>(src, dst, per_blk, cb_dst, cb_src, pairs, skeys, E);
    finalize_csr_kernel<<<NBUK, 256, 0, stream>>>(pairs, skeys, cb_dst, cb_src, feat,
                                                  row_ptr, col, dinv, hsA, N);

    const int FG = 1024;   // == resident capacity at 4 waves/SIMD; do NOT exceed
    fused_kernel<<<FG, 256, 0, stream>>>(hsA, row_ptr, col, W0, b0, dinv, nullptr, hsB, msum, N, 0);
    fused_kernel<<<FG, 256, 0, stream>>>(hsB, row_ptr, col, W1, b1, dinv, nullptr, hsA, msum, N, 0);
    fused_kernel<<<FG, 256, 0, stream>>>(hsA, row_ptr, col, W2, b2, dinv, out, nullptr, msum, N, 1);

    finalize_kernel<<<1, 64, 0, stream>>>(msum, out + (size_t)N * D, 1.0f / (float)N);
}